// Round 1
// 496.021 us; speedup vs baseline: 1.1678x; 1.1678x over previous
//
#include <hip/hip_runtime.h>
#include <hip/hip_bf16.h>
#include <stdint.h>

#define IN_F 4096
#define OUT_F 4096

typedef __attribute__((ext_vector_type(8))) __bf16 bf16x8;
typedef __attribute__((ext_vector_type(4))) float f32x4;

__device__ __forceinline__ void gl_lds_16(const void* g, void* l) {
    __builtin_amdgcn_global_load_lds((const __attribute__((address_space(1))) void*)g,
                                     (__attribute__((address_space(3))) void*)l,
                                     16, 0, 0);
}

// ---- fused: x fp32->bf16 (8 elems/thread, 16B stores) + sorted-COO scatter ----
// (unchanged from previous round; its dispatch counters get read next round)
__global__ void cvt_and_scatter(const float* __restrict__ x, __bf16* __restrict__ Xb, int n8,
                                const float* __restrict__ vals, const int* __restrict__ idx,
                                __bf16* __restrict__ W, int nnz, int cvtBlocks) {
    if ((int)blockIdx.x < cvtBlocks) {
        int i = blockIdx.x * blockDim.x + threadIdx.x;
        if (i < n8) {
            const float4* src = (const float4*)(x + (size_t)i * 8);
            float4 v0 = src[0], v1 = src[1];
            bf16x8 o;
            o[0] = (__bf16)v0.x; o[1] = (__bf16)v0.y; o[2] = (__bf16)v0.z; o[3] = (__bf16)v0.w;
            o[4] = (__bf16)v1.x; o[5] = (__bf16)v1.y; o[6] = (__bf16)v1.z; o[7] = (__bf16)v1.w;
            *(bf16x8*)(Xb + (size_t)i * 8) = o;
        }
    } else {
        int i = (blockIdx.x - cvtBlocks) * blockDim.x + threadIdx.x;
        if (i >= nnz) return;
        const int id = idx[i];
        if (i > 0 && idx[i - 1] == id) return;
        float s = vals[i];
        for (int j = i + 1; j < nnz && idx[j] == id; ++j) s += vals[j];
        W[id] = (__bf16)s;
    }
}

// ---- GEMM: C[M,N] = A[M,K] * B[N,K]^T + bias,  bf16 in / fp32 out ----
// 256x256 tile, BK=32, 8 waves (2Mx4N), quad-buffered LDS (4 x 32KB = 128KB),
// prefetch distance 3 K-tiles, counted s_waitcnt vmcnt(8) (never 0 in main loop),
// raw s_barrier (NOT __syncthreads -> no vmcnt(0) drain), setprio(1) around MFMA.
// No LDS swizzle needed: BK=32 row stride (64B) flips bank bit4 with row parity ->
// ds_read_b128 quadrant reads are already uniform 8 words/bank (structural min).
#define BM 256
#define BN 256
#define BK 32
#define NT (IN_F / BK)   // 128 K-tiles

__global__ __launch_bounds__(512, 2) void gemm_bf16_bt(
    const __bf16* __restrict__ A, const __bf16* __restrict__ B,
    const float* __restrict__ bias, float* __restrict__ C,
    int M, int N, int K)
{
    // 4 buffers x { sA: 256x32 | sB: 256x32 } bf16 = 4 x 32KB = 128KB static LDS
    __shared__ __align__(128) __bf16 lds[4][16384];

    const int t512 = threadIdx.x;          // 0..511
    const int wave = t512 >> 6;            // 0..7
    const int lane = t512 & 63;
    const int wm = wave >> 2;              // 0..1  (M half)
    const int wn = wave & 3;               // 0..3  (N quarter)
    const int lq = lane >> 4;              // 0..3
    const int lr = lane & 15;              // 0..15

    // XCD swizzle: grid is exactly 512 = 8 XCDs x 64 contiguous slots
    const int bid  = blockIdx.x;
    const int wgid = (bid & 7) * 64 + (bid >> 3);
    const int mt = wgid >> 4;              // 0..31  (M tiles; nt walks fastest -> A panel stays in XCD L2)
    const int nt = wgid & 15;              // 0..15  (N tiles)
    const int tileM = mt * BM;
    const int tileN = nt * BN;

    // staging: per 8KB issue, thread u covers row u>>2 (128 rows), 16B chunk (u&3).
    // LDS dest = base + u*16B  == wave-uniform base + lane*16 (global_load_lds constraint).
    const int srow = t512 >> 2;            // 0..127
    const int scol = (t512 & 3) * 8;       // element col: 0,8,16,24

    const __bf16* gA0 = A + (size_t)(tileM + srow) * K + scol;
    const __bf16* gA1 = A + (size_t)(tileM + 128 + srow) * K + scol;
    const __bf16* gB0 = B + (size_t)(tileN + srow) * K + scol;
    const __bf16* gB1 = B + (size_t)(tileN + 128 + srow) * K + scol;

#define STAGE_A(buf, k0) do { \
        gl_lds_16(gA0 + (k0), &lds[buf][0]    + t512 * 8); \
        gl_lds_16(gA1 + (k0), &lds[buf][4096] + t512 * 8); } while (0)
#define STAGE_B(buf, k0) do { \
        gl_lds_16(gB0 + (k0), &lds[buf][8192]         + t512 * 8); \
        gl_lds_16(gB1 + (k0), &lds[buf][8192 + 4096]  + t512 * 8); } while (0)

    // per-wave fragment read offsets (elements)
    const int aoff = (wm * 128 + lr) * BK + lq * 8;          // A rows wm*128 + mi*16 + lr
    const int boff = 8192 + (wn * 64 + lr) * BK + lq * 8;    // B rows wn*64  + ni*16 + lr

    f32x4 acc[8][4] = {};

    // ---- prologue: stage tiles 0,1,2 (12 issues); wait own tile-0 loads; sync ----
    STAGE_A(0, 0);   STAGE_B(0, 0);
    STAGE_A(1, 32);  STAGE_B(1, 32);
    STAGE_A(2, 64);  STAGE_B(2, 64);
    asm volatile("s_waitcnt vmcnt(8)" ::: "memory");
    __builtin_amdgcn_s_barrier();
    asm volatile("" ::: "memory");

    for (int t = 0; t < NT; ++t) {
        const __bf16* sbuf = &lds[t & 3][0];
        const int  pk = (t + 3) * BK;
        const int  pb = (t + 3) & 3;       // == (t-1)&3: that buffer's reads all完成 at t-1's closing barrier
        const bool pf = (t + 3) < NT;

        // ================= Phase 0: quadrant mi0-3 x ni0-3 =================
        bf16x8 af[4], bg[4];
#pragma unroll
        for (int mi = 0; mi < 4; ++mi) af[mi] = *(const bf16x8*)&sbuf[aoff + mi * 512];
#pragma unroll
        for (int ni = 0; ni < 4; ++ni) bg[ni] = *(const bf16x8*)&sbuf[boff + ni * 512];
        if (pf) STAGE_A(pb, pk);
        asm volatile("" ::: "memory");
        __builtin_amdgcn_s_barrier();
        asm volatile("" ::: "memory");
        __builtin_amdgcn_s_setprio(1);
#pragma unroll
        for (int mi = 0; mi < 4; ++mi)
#pragma unroll
            for (int ni = 0; ni < 4; ++ni)
                acc[mi][ni] = __builtin_amdgcn_mfma_f32_16x16x32_bf16(af[mi], bg[ni], acc[mi][ni], 0, 0, 0);
        __builtin_amdgcn_s_setprio(0);
        asm volatile("" ::: "memory");
        __builtin_amdgcn_s_barrier();
        asm volatile("" ::: "memory");

        // ================= Phase 1: quadrant mi4-7 x ni0-3 (bg reused) ======
        bf16x8 af2[4];
#pragma unroll
        for (int mi = 0; mi < 4; ++mi) af2[mi] = *(const bf16x8*)&sbuf[aoff + 2048 + mi * 512];
        if (pf) STAGE_B(pb, pk);
        asm volatile("" ::: "memory");
        __builtin_amdgcn_s_barrier();
        asm volatile("" ::: "memory");
        __builtin_amdgcn_s_setprio(1);
#pragma unroll
        for (int mi = 0; mi < 4; ++mi)
#pragma unroll
            for (int ni = 0; ni < 4; ++ni)
                acc[mi + 4][ni] = __builtin_amdgcn_mfma_f32_16x16x32_bf16(af2[mi], bg[ni], acc[mi + 4][ni], 0, 0, 0);
        __builtin_amdgcn_s_setprio(0);
        // counted wait: own tile-(t+1) loads landed; closing barrier => ALL waves' landed.
        // steady state leaves tiles t+2,t+3 (8 loads) in flight; drain only at the tail.
        if (t < NT - 3)       asm volatile("s_waitcnt vmcnt(8)" ::: "memory");
        else if (t == NT - 3) asm volatile("s_waitcnt vmcnt(4)" ::: "memory");
        else if (t == NT - 2) asm volatile("s_waitcnt vmcnt(0)" ::: "memory");
        __builtin_amdgcn_s_barrier();
        asm volatile("" ::: "memory");
    }

    // ---- epilogue: C/D layout col=lane&15, row=(lane>>4)*4+reg  [m89-verified] ----
    float bv[4];
#pragma unroll
    for (int ni = 0; ni < 4; ++ni) bv[ni] = bias[tileN + wn * 64 + ni * 16 + lr];
#pragma unroll
    for (int mi = 0; mi < 8; ++mi) {
#pragma unroll
        for (int ni = 0; ni < 4; ++ni) {
            const int gn = tileN + wn * 64 + ni * 16 + lr;
#pragma unroll
            for (int r = 0; r < 4; ++r) {
                const int gm = tileM + wm * 128 + mi * 16 + lq * 4 + r;
                C[(size_t)gm * N + gn] = acc[mi][ni][r] + bv[ni];
            }
        }
    }
#undef STAGE_A
#undef STAGE_B
}

extern "C" void kernel_launch(void* const* d_in, const int* in_sizes, int n_in,
                              void* d_out, int out_size, void* d_ws, size_t ws_size,
                              hipStream_t stream) {
    const float* x    = (const float*)d_in[0];   // (4,2048,4096) fp32
    const float* vals = (const float*)d_in[1];   // (NNZ,) fp32
    const float* bias = (const float*)d_in[2];   // (4096,) fp32
    const int*   idx  = (const int*)d_in[3];     // (NNZ,) sorted flat indices (int32: jax x64 off)
    float* out = (float*)d_out;                  // (4,2048,4096) fp32

    const int nnz = in_sizes[1];
    const int K = IN_F, N = OUT_F;
    const int M = in_sizes[0] / K;               // 8192

    // workspace: [0,32M) W bf16 | [32M,96M) x bf16
    char* ws = (char*)d_ws;
    __bf16* Wb = (__bf16*)ws;
    __bf16* Xb = (__bf16*)(ws + (size_t)32 * 1024 * 1024);

    const int wElems = N * K;                    // 16777216
    const int xElems = M * K;                    // 33554432
    const int n8 = xElems / 8;                   // 4194304 cvt threads
    const int cvtBlocks = n8 / 256;              // 16384
    const int scatBlocks = (nnz + 255) / 256;    // 6554

    hipMemsetAsync(Wb, 0, (size_t)wElems * sizeof(__bf16), stream);
    cvt_and_scatter<<<cvtBlocks + scatBlocks, 256, 0, stream>>>(
        x, Xb, n8, vals, idx, Wb, nnz, cvtBlocks);

    gemm_bf16_bt<<<(M / BM) * (N / BN), 512, 0, stream>>>(Xb, Wb, bias, out, M, N, K);
}

// Round 3
// 486.802 us; speedup vs baseline: 1.1900x; 1.0189x over previous
//
#include <hip/hip_runtime.h>
#include <hip/hip_bf16.h>
#include <stdint.h>

#define IN_F 4096
#define OUT_F 4096

typedef __attribute__((ext_vector_type(8))) __bf16 bf16x8;
typedef __attribute__((ext_vector_type(4))) float f32x4;

__device__ __forceinline__ void gl_lds_16(const void* g, void* l) {
    __builtin_amdgcn_global_load_lds((const __attribute__((address_space(1))) void*)g,
                                     (__attribute__((address_space(3))) void*)l,
                                     16, 0, 0);
}

// ---- fused: x fp32->bf16 (8 elems/thread, 16B stores) + sorted-COO scatter ----
__global__ void cvt_and_scatter(const float* __restrict__ x, __bf16* __restrict__ Xb, int n8,
                                const float* __restrict__ vals, const int* __restrict__ idx,
                                __bf16* __restrict__ W, int nnz, int cvtBlocks) {
    if ((int)blockIdx.x < cvtBlocks) {
        int i = blockIdx.x * blockDim.x + threadIdx.x;
        if (i < n8) {
            const float4* src = (const float4*)(x + (size_t)i * 8);
            float4 v0 = src[0], v1 = src[1];
            bf16x8 o;
            o[0] = (__bf16)v0.x; o[1] = (__bf16)v0.y; o[2] = (__bf16)v0.z; o[3] = (__bf16)v0.w;
            o[4] = (__bf16)v1.x; o[5] = (__bf16)v1.y; o[6] = (__bf16)v1.z; o[7] = (__bf16)v1.w;
            *(bf16x8*)(Xb + (size_t)i * 8) = o;
        }
    } else {
        // flat_idx sorted -> duplicate runs adjacent; run owner sums fp32, stores bf16.
        int i = (blockIdx.x - cvtBlocks) * blockDim.x + threadIdx.x;
        if (i >= nnz) return;
        const int id = idx[i];
        if (i > 0 && idx[i - 1] == id) return;
        float s = vals[i];
        for (int j = i + 1; j < nnz && idx[j] == id; ++j) s += vals[j];
        W[id] = (__bf16)s;
    }
}

// ---- GEMM: C[M,N] = A[M,K] * B[N,K]^T + bias,  bf16 in / fp32 out ----
// 256x256 tile, BK=32, 8 waves (2Mx4N), quad-buffered LDS (4 x 32KB = 128KB),
// prefetch distance 3, counted vmcnt(8) in steady state.
// ONE barrier per K-tile (R2 schedule, resubmitted after infra flake). Hazards:
//   WAR: STAGE(t) DMA-writes buf (t-1)&3, last ds_read during tile t-1 ->
//        explicit lgkmcnt(0) + s_barrier at end of each tile separates them.
//   RAW: reads(t) need buf t&3 staged at t-3 -> vmcnt(8) before that barrier
//        (4 loads/thread/tile; in-flight at wait = tiles t,t-1 = 8).
// All 12 fragment ds_reads + 4 STAGE issues go up front; wave skew overlaps
// the LDS pipe (~1150 cyc/K-tile) against the MFMA pipe (~1240 cyc/K-tile)
// instead of serializing them in barrier-locked phases.
#define BM 256
#define BN 256
#define BK 32
#define NT (IN_F / BK)   // 128 K-tiles

__global__ __launch_bounds__(512, 2) void gemm_bf16_bt(
    const __bf16* __restrict__ A, const __bf16* __restrict__ B,
    const float* __restrict__ bias, float* __restrict__ C,
    int M, int N, int K)
{
    __shared__ __align__(128) __bf16 lds[4][16384];

    const int t512 = threadIdx.x;          // 0..511
    const int wave = t512 >> 6;            // 0..7
    const int lane = t512 & 63;
    const int wm = wave >> 2;              // 0..1  (M half)
    const int wn = wave & 3;               // 0..3  (N quarter)
    const int lq = lane >> 4;              // 0..3
    const int lr = lane & 15;              // 0..15

    // XCD swizzle: grid is exactly 512 = 8 XCDs x 64 contiguous slots
    const int bid  = blockIdx.x;
    const int wgid = (bid & 7) * 64 + (bid >> 3);
    const int mt = wgid >> 4;              // 0..31
    const int nt = wgid & 15;              // 0..15
    const int tileM = mt * BM;
    const int tileN = nt * BN;

    // staging: thread u covers row u>>2, 16B chunk (u&3); LDS dest = base + u*16B.
    const int srow = t512 >> 2;            // 0..127
    const int scol = (t512 & 3) * 8;       // element col: 0,8,16,24

    const __bf16* gA0 = A + (size_t)(tileM + srow) * K + scol;
    const __bf16* gA1 = A + (size_t)(tileM + 128 + srow) * K + scol;
    const __bf16* gB0 = B + (size_t)(tileN + srow) * K + scol;
    const __bf16* gB1 = B + (size_t)(tileN + 128 + srow) * K + scol;

#define STAGE_A(buf, k0) do { \
        gl_lds_16(gA0 + (k0), &lds[buf][0]    + t512 * 8); \
        gl_lds_16(gA1 + (k0), &lds[buf][4096] + t512 * 8); } while (0)
#define STAGE_B(buf, k0) do { \
        gl_lds_16(gB0 + (k0), &lds[buf][8192]         + t512 * 8); \
        gl_lds_16(gB1 + (k0), &lds[buf][8192 + 4096]  + t512 * 8); } while (0)

    // per-wave fragment read offsets (elements)
    const int aoff = (wm * 128 + lr) * BK + lq * 8;          // A row block, af[mi] at +mi*512
    const int boff = 8192 + (wn * 64 + lr) * BK + lq * 8;    // B row block, bg[ni] at +ni*512

    f32x4 acc[8][4] = {};

    // ---- prologue: stage tiles 0,1,2; wait tile-0 loads; sync ----
    STAGE_A(0, 0);   STAGE_B(0, 0);
    STAGE_A(1, 32);  STAGE_B(1, 32);
    STAGE_A(2, 64);  STAGE_B(2, 64);
    asm volatile("s_waitcnt vmcnt(8)" ::: "memory");
    __builtin_amdgcn_s_barrier();
    asm volatile("" ::: "memory");

    for (int t = 0; t < NT; ++t) {
        const __bf16* sbuf = &lds[t & 3][0];
        const int  pk = (t + 3) * BK;
        const int  pb = (t + 3) & 3;       // == (t-1)&3: safe, its readers drained at t-1's barrier
        const bool pf = (t + 3) < NT;

        // issue prefetch first (longest latency), then all 12 fragment reads
        if (pf) { STAGE_A(pb, pk); STAGE_B(pb, pk); }

        bf16x8 af[8], bg[4];
#pragma unroll
        for (int mi = 0; mi < 8; ++mi) af[mi] = *(const bf16x8*)&sbuf[aoff + mi * 512];
#pragma unroll
        for (int ni = 0; ni < 4; ++ni) bg[ni] = *(const bf16x8*)&sbuf[boff + ni * 512];

        __builtin_amdgcn_s_setprio(1);
#pragma unroll
        for (int mi = 0; mi < 8; ++mi)
#pragma unroll
            for (int ni = 0; ni < 4; ++ni)
                acc[mi][ni] = __builtin_amdgcn_mfma_f32_16x16x32_bf16(af[mi], bg[ni], acc[mi][ni], 0, 0, 0);
        __builtin_amdgcn_s_setprio(0);

        // drain own ds_reads (consumed by MFMA already -> free), then counted vmcnt:
        // steady state leaves tiles t+2,t+3 (8 loads) in flight; drain only at tail.
        asm volatile("s_waitcnt lgkmcnt(0)" ::: "memory");
        if (t < NT - 3)       asm volatile("s_waitcnt vmcnt(8)" ::: "memory");
        else if (t == NT - 3) asm volatile("s_waitcnt vmcnt(4)" ::: "memory");
        else if (t == NT - 2) asm volatile("s_waitcnt vmcnt(0)" ::: "memory");
        __builtin_amdgcn_s_barrier();
        asm volatile("" ::: "memory");
    }

    // ---- epilogue: C/D layout col=lane&15, row=(lane>>4)*4+reg  [m89-verified] ----
    float bv[4];
#pragma unroll
    for (int ni = 0; ni < 4; ++ni) bv[ni] = bias[tileN + wn * 64 + ni * 16 + lr];
#pragma unroll
    for (int mi = 0; mi < 8; ++mi) {
#pragma unroll
        for (int ni = 0; ni < 4; ++ni) {
            const int gn = tileN + wn * 64 + ni * 16 + lr;
#pragma unroll
            for (int r = 0; r < 4; ++r) {
                const int gm = tileM + wm * 128 + mi * 16 + lq * 4 + r;
                C[(size_t)gm * N + gn] = acc[mi][ni][r] + bv[ni];
            }
        }
    }
#undef STAGE_A
#undef STAGE_B
}

extern "C" void kernel_launch(void* const* d_in, const int* in_sizes, int n_in,
                              void* d_out, int out_size, void* d_ws, size_t ws_size,
                              hipStream_t stream) {
    const float* x    = (const float*)d_in[0];   // (4,2048,4096) fp32
    const float* vals = (const float*)d_in[1];   // (NNZ,) fp32
    const float* bias = (const float*)d_in[2];   // (4096,) fp32
    const int*   idx  = (const int*)d_in[3];     // (NNZ,) sorted flat indices
    float* out = (float*)d_out;                  // (4,2048,4096) fp32

    const int nnz = in_sizes[1];
    const int K = IN_F, N = OUT_F;
    const int M = in_sizes[0] / K;               // 8192

    // workspace: [0,32M) W bf16 | [32M,96M) x bf16
    char* ws = (char*)d_ws;
    __bf16* Wb = (__bf16*)ws;
    __bf16* Xb = (__bf16*)(ws + (size_t)32 * 1024 * 1024);

    const int wElems = N * K;                    // 16777216
    const int xElems = M * K;                    // 33554432
    const int n8 = xElems / 8;                   // 4194304 cvt threads
    const int cvtBlocks = n8 / 256;              // 16384
    const int scatBlocks = (nnz + 255) / 256;    // 6554

    hipMemsetAsync(Wb, 0, (size_t)wElems * sizeof(__bf16), stream);
    cvt_and_scatter<<<cvtBlocks + scatBlocks, 256, 0, stream>>>(
        x, Xb, n8, vals, idx, Wb, nnz, cvtBlocks);

    gemm_bf16_bt<<<(M / BM) * (N / BN), 512, 0, stream>>>(Xb, Wb, bias, out, M, N, K);
}